// Round 2
// baseline (281.791 us; speedup 1.0000x reference)
//
#include <hip/hip_runtime.h>
#include <hip/hip_cooperative_groups.h>

namespace cg = cooperative_groups;

typedef __attribute__((ext_vector_type(8))) short short8;   // 8 x bf16 = 4 VGPR (MFMA A/B frag)
typedef __attribute__((ext_vector_type(4))) float floatx4;  // MFMA C/D frag

__device__ __forceinline__ float fast_exp2(float x) { return __builtin_amdgcn_exp2f(x); }
__device__ __forceinline__ float fast_rcp(float x)  { return __builtin_amdgcn_rcpf(x); }

// fp32 -> bf16 round-to-nearest-even (no inf/nan in this data)
__device__ __forceinline__ unsigned short f2bf(float f) {
    union { float f; unsigned u; } v; v.f = f;
    unsigned u = v.u;
    return (unsigned short)((u + 0x7FFFu + ((u >> 16) & 1u)) >> 16);
}

#define B_DIM   256
#define IN_DIM  1024
#define OUT_DIM 1024
#define NK      5               // odd powers z^1..z^9
#define KFEAT   (NK * IN_DIM)   // 5120
#define LOG2E   1.4426950408889634f

#define NSEG    8               // global K-segments (one partial slab each)
#define SEGK    (KFEAT / NSEG)  // 640 shorts per block
#define WSEGK   (SEGK / 4)      // 160 shorts per wave (5 K-steps of 32)

// Exact Taylor coefficients of tanh: z - z^3/3 + 2z^5/15 - 17z^7/315 + 62z^9/2835
#define TC0 (1.0f)
#define TC1 (-0.3333333333f)
#define TC2 (0.1333333333f)
#define TC3 (-0.05396825397f)
#define TC4 (0.02186948853f)

// ---------------------------------------------------------------------------
// Phase bodies as __device__ functions, shared by the fused cooperative kernel
// and the 3-kernel fallback path.
// ---------------------------------------------------------------------------

// Bf[o][s*1024+i] = bf16(C_s * w_eff^(2s+1)), w_eff = softmax(fl).[w,tanh w,sin w]
__device__ __forceinline__ void bf_unit(int o, int tid,
                                        const float* __restrict__ W,
                                        const float* __restrict__ fl,
                                        unsigned short* __restrict__ Bf)
{
    const int j4 = o * 256 + tid;                    // o = j4>>8, 4 i-columns per thread
    const int i  = (j4 & 255) * 4;
    const float4* fl4 = (const float4*)fl;
    float4 f0 = fl4[3 * j4 + 0];
    float4 f1 = fl4[3 * j4 + 1];
    float4 f2 = fl4[3 * j4 + 2];
    float4 w4 = ((const float4*)W)[j4];

    float l[4][3] = {{f0.x, f0.y, f0.z},
                     {f0.w, f1.x, f1.y},
                     {f1.z, f1.w, f2.x},
                     {f2.y, f2.z, f2.w}};
    float wv[4] = {w4.x, w4.y, w4.z, w4.w};
    const float C[NK] = {TC0, TC1, TC2, TC3, TC4};

    float we[4], tt[4];
#pragma unroll
    for (int e = 0; e < 4; ++e) {
        float e0 = fast_exp2(l[e][0] * LOG2E);
        float e1 = fast_exp2(l[e][1] * LOG2E);
        float e2 = fast_exp2(l[e][2] * LOG2E);
        float inv = fast_rcp(e0 + e1 + e2);
        float w = wv[e];
        float t = w * w;
        float th = w * (1.0f + t * (-0.3333333333f + t * (0.1333333333f + t * (-0.05396825397f))));
        float sn = w * (1.0f + t * (-0.1666666667f + t * (0.008333333333f + t * (-1.984126984e-4f))));
        we[e] = (e0 * w + e1 * th + e2 * sn) * inv;
        tt[e] = we[e] * we[e];
    }
#pragma unroll
    for (int s = 0; s < NK; ++s) {
        ushort4 u = make_ushort4(f2bf(C[s] * we[0]), f2bf(C[s] * we[1]),
                                 f2bf(C[s] * we[2]), f2bf(C[s] * we[3]));
        *(ushort4*)(Bf + (size_t)o * KFEAT + s * IN_DIM + i) = u;
#pragma unroll
        for (int e = 0; e < 4; ++e) we[e] *= tt[e];
    }
}

// Af[b][s*1024+i] = bf16(h[b,i]^(2s+1))
__device__ __forceinline__ void af_unit(int b, int tid,
                                        const float* __restrict__ h,
                                        unsigned short* __restrict__ Af)
{
    const int j4 = b * 256 + tid;
    const int i  = (j4 & 255) * 4;
    float4 hv = ((const float4*)h)[j4];
    float x[4] = {hv.x, hv.y, hv.z, hv.w};
    float p[4], t[4];
#pragma unroll
    for (int e = 0; e < 4; ++e) { p[e] = x[e]; t[e] = x[e] * x[e]; }
#pragma unroll
    for (int s = 0; s < NK; ++s) {
        ushort4 u = make_ushort4(f2bf(p[0]), f2bf(p[1]), f2bf(p[2]), f2bf(p[3]));
        *(ushort4*)(Af + (size_t)b * KFEAT + s * IN_DIM + i) = u;
#pragma unroll
        for (int e = 0; e < 4; ++e) p[e] *= t[e];
    }
}

// Split-K GEMM tile: part[sg] = Af(256x5120).Bf(1024x5120)^T over K-segment sg.
// 512 blocks = 8(K-seg) x 4(M) x 16(N), 64x64 tiles, 4 waves x 160-K each.
// Two-stage LDS reduce in 32 KB (waves 0/1 store, waves 2/3 accumulate) so the
// cooperative launch occupancy check passes at 2 blocks/CU even under a 64 KB
// per-CU shared-memory accounting.
// mfma_f32_16x16x32_bf16: A/B frag elem [m|n=lane&15][k=(lane>>4)*8+j];
// C/D: row=(lane>>4)*4+reg, col=lane&15 (verified prev session R4-R6).
__device__ __forceinline__ void gemm_body(int bx, int tid,
                                          const unsigned short* __restrict__ Af,
                                          const unsigned short* __restrict__ Bf,
                                          float* __restrict__ part,
                                          float* red /* 2*4096 floats LDS */)
{
    const int sg = bx & 7;                   // global K-segment
    const int tm = (bx >> 3) & 3;            // M-tile (64 rows)
    const int tn = bx >> 5;                  // N-tile (64 cols)
    const int w    = tid >> 6;               // local K-split
    const int lane = tid & 63;
    const int q    = lane >> 4;
    const int ln   = lane & 15;

    const int kstart = sg * SEGK + w * WSEGK + q * 8;   // in shorts

    const short8* Ar[4];
    const short8* Br[4];
#pragma unroll
    for (int g = 0; g < 4; ++g)
        Ar[g] = (const short8*)(Af + (size_t)(tm * 64 + g * 16 + ln) * KFEAT + kstart);
#pragma unroll
    for (int c = 0; c < 4; ++c)
        Br[c] = (const short8*)(Bf + (size_t)(tn * 64 + c * 16 + ln) * KFEAT + kstart);

    floatx4 acc[4][4];
#pragma unroll
    for (int g = 0; g < 4; ++g)
#pragma unroll
        for (int c = 0; c < 4; ++c) acc[g][c] = (floatx4)(0.0f);

#pragma unroll
    for (int kk = 0; kk < WSEGK; kk += 32) {             // 5 steps, full unroll
        short8 a[4], b[4];
#pragma unroll
        for (int g = 0; g < 4; ++g) a[g] = Ar[g][kk >> 3];
#pragma unroll
        for (int c = 0; c < 4; ++c) b[c] = Br[c][kk >> 3];
#pragma unroll
        for (int g = 0; g < 4; ++g)
#pragma unroll
            for (int c = 0; c < 4; ++c)
                acc[g][c] = __builtin_amdgcn_mfma_f32_16x16x32_bf16(a[g], b[c], acc[g][c], 0, 0, 0);
    }

    // two-stage cross-wave reduce in 32 KB LDS
    float* buf = red + (size_t)(w & 1) * 4096;
    if (w < 2) {
#pragma unroll
        for (int g = 0; g < 4; ++g)
#pragma unroll
            for (int c = 0; c < 4; ++c)
#pragma unroll
                for (int r = 0; r < 4; ++r)
                    buf[(g * 16 + q * 4 + r) * 64 + (c * 16 + ln)] = acc[g][c][r];
    }
    __syncthreads();
    if (w >= 2) {
#pragma unroll
        for (int g = 0; g < 4; ++g)
#pragma unroll
            for (int c = 0; c < 4; ++c)
#pragma unroll
                for (int r = 0; r < 4; ++r)
                    buf[(g * 16 + q * 4 + r) * 64 + (c * 16 + ln)] += acc[g][c][r];
    }
    __syncthreads();

    // final pairwise sum + ONE plain store per output; j-major => coalesced
    float* pseg = part + (size_t)sg * (B_DIM * OUT_DIM);
#pragma unroll
    for (int j = 0; j < 16; ++j) {
        const int idx = j * 256 + tid;               // 0..4095
        const float v = red[idx] + red[4096 + idx];
        const int lr = idx >> 6, lc = idx & 63;
        pseg[(size_t)(tm * 64 + lr) * OUT_DIM + tn * 64 + lc] = v;
    }
}

// out = bias + sum over 8 partial slabs (one block-unit = 256 float4s)
__device__ __forceinline__ void reduce_body(int bx, int tid,
                                            const float* __restrict__ part,
                                            const float* __restrict__ bias,
                                            float* __restrict__ out)
{
    const int j4 = bx * 256 + tid;                   // 65536 float4s total
    float4 a = ((const float4*)bias)[j4 & 255];
#pragma unroll
    for (int s = 0; s < NSEG; ++s) {
        float4 p = ((const float4*)part)[s * 65536 + j4];
        a.x += p.x; a.y += p.y; a.z += p.z; a.w += p.w;
    }
    ((float4*)out)[j4] = a;
}

// ---------------------------------------------------------------------------
// Fused cooperative kernel: 512 blocks x 256 threads, 2 blocks/CU.
//   phase 1: features (blocks 0..511 do Bf rows {bx, bx+512}; 0..255 also Af)
//   phase 2: split-K GEMM -> partial slabs
//   phase 3: blocks 0..255 reduce slabs + bias -> out
// ---------------------------------------------------------------------------
__global__ __launch_bounds__(256, 2) void fused_all(
    const float* __restrict__ h, const float* __restrict__ W,
    const float* __restrict__ fl, const float* __restrict__ bias,
    unsigned short* __restrict__ Af, unsigned short* __restrict__ Bf,
    float* __restrict__ part, float* __restrict__ out)
{
    __shared__ float red[2 * 4096];                  // 32 KB
    const int bx  = blockIdx.x;
    const int tid = threadIdx.x;
    cg::grid_group grid = cg::this_grid();

    bf_unit(bx, tid, W, fl, Bf);
    bf_unit(bx + 512, tid, W, fl, Bf);
    if (bx < 256) af_unit(bx, tid, h, Af);

    __threadfence();
    grid.sync();

    gemm_body(bx, tid, Af, Bf, part, red);

    __threadfence();
    grid.sync();

    if (bx < 256) reduce_body(bx, tid, part, bias, out);
}

// ---------------------------------------------------------------------------
// Fallback path (verified R1 pipeline), used if cooperative launch is refused.
// ---------------------------------------------------------------------------
__global__ __launch_bounds__(256) void feat_fused_kernel(
    const float* __restrict__ h, const float* __restrict__ W,
    const float* __restrict__ fl,
    unsigned short* __restrict__ Af, unsigned short* __restrict__ Bf)
{
    if (blockIdx.x < 1024) bf_unit(blockIdx.x, threadIdx.x, W, fl, Bf);
    else                   af_unit(blockIdx.x - 1024, threadIdx.x, h, Af);
}

__global__ __launch_bounds__(256, 2) void gemm_feat_kernel(
    const unsigned short* __restrict__ Af,
    const unsigned short* __restrict__ Bf,
    float* __restrict__ part)
{
    __shared__ float red[2 * 4096];
    gemm_body(blockIdx.x, threadIdx.x, Af, Bf, part, red);
}

__global__ __launch_bounds__(256) void reduce_bias_kernel(
    const float* __restrict__ part, const float* __restrict__ bias,
    float* __restrict__ out)
{
    reduce_body(blockIdx.x, threadIdx.x, part, bias, out);
}

extern "C" void kernel_launch(void* const* d_in, const int* in_sizes, int n_in,
                              void* d_out, int out_size, void* d_ws, size_t ws_size,
                              hipStream_t stream) {
    const float* h  = (const float*)d_in[0];   // (256, 1024)
    const float* W  = (const float*)d_in[1];   // (1024, 1024)
    const float* b  = (const float*)d_in[2];   // (1024,)
    const float* fl = (const float*)d_in[3];   // (1024, 1024, 3)
    float* out = (float*)d_out;                // (256, 1024)

    unsigned short* Af = (unsigned short*)d_ws;            // 2.5 MB
    unsigned short* Bf = Af + (size_t)B_DIM * KFEAT;       // 10 MB
    float* part = (float*)(Bf + (size_t)OUT_DIM * KFEAT);  // 8 MB fp32 partials

    void* args[] = {(void*)&h, (void*)&W, (void*)&fl, (void*)&b,
                    (void*)&Af, (void*)&Bf, (void*)&part, (void*)&out};
    hipError_t e = hipLaunchCooperativeKernel((const void*)fused_all,
                                              dim3(512), dim3(256),
                                              args, 0, stream);
    if (e != hipSuccess) {
        // fallback: verified three-kernel pipeline (R1)
        feat_fused_kernel<<<1280, 256, 0, stream>>>(h, W, fl, Af, Bf);
        gemm_feat_kernel<<<512, 256, 0, stream>>>(Af, Bf, part);
        reduce_bias_kernel<<<256, 256, 0, stream>>>(part, b, out);
    }
}

// Round 3
// 86.797 us; speedup vs baseline: 3.2466x; 3.2466x over previous
//
#include <hip/hip_runtime.h>

typedef __attribute__((ext_vector_type(8))) short short8;   // 8 x bf16 = 4 VGPR (MFMA A/B frag)
typedef __attribute__((ext_vector_type(4))) float floatx4;  // MFMA C/D frag

__device__ __forceinline__ float fast_exp2(float x) { return __builtin_amdgcn_exp2f(x); }
__device__ __forceinline__ float fast_rcp(float x)  { return __builtin_amdgcn_rcpf(x); }

// fp32 -> bf16 round-to-nearest-even (no inf/nan in this data)
__device__ __forceinline__ unsigned short f2bf(float f) {
    union { float f; unsigned u; } v; v.f = f;
    unsigned u = v.u;
    return (unsigned short)((u + 0x7FFFu + ((u >> 16) & 1u)) >> 16);
}

#define B_DIM   256
#define IN_DIM  1024
#define OUT_DIM 1024
#define NK      5               // odd powers z^1..z^9
#define KFEAT   (NK * IN_DIM)   // 5120
#define LOG2E   1.4426950408889634f

#define NSEG    8               // global K-segments (one partial slab each)
#define SEGK    (KFEAT / NSEG)  // 640 shorts per block
#define WSEGK   (SEGK / 4)      // 160 shorts per wave (5 K-steps of 32)

// Exact Taylor coefficients of tanh: z - z^3/3 + 2z^5/15 - 17z^7/315 + 62z^9/2835
#define TC0 (1.0f)
#define TC1 (-0.3333333333f)
#define TC2 (0.1333333333f)
#define TC3 (-0.05396825397f)
#define TC4 (0.02186948853f)

// ---------------------------------------------------------------------------
// Fused feature kernel (ONE dispatch):
//   blocks [0,1024)    : Bf[o][s*1024+i] = bf16(C_s * w_eff^(2s+1)),
//                        w_eff = softmax(f_logits).[w, tanh w, sin w]
//   blocks [1024,1280) : Af[b][s*1024+i] = bf16(h[b,i]^(2s+1))
// ---------------------------------------------------------------------------
__global__ __launch_bounds__(256) void feat_fused_kernel(
    const float* __restrict__ h,           // (256, 1024)
    const float* __restrict__ W,           // (1024, 1024)
    const float* __restrict__ fl,          // (1024, 1024, 3)
    unsigned short* __restrict__ Af,       // (256, 5120) bf16
    unsigned short* __restrict__ Bf)       // (1024, 5120) bf16
{
    if (blockIdx.x < 1024) {
        const int j4 = blockIdx.x * 256 + threadIdx.x;   // 262144 float4-chunks
        const int o  = j4 >> 8;
        const int i  = (j4 & 255) * 4;
        const float4* fl4 = (const float4*)fl;
        float4 f0 = fl4[3 * j4 + 0];
        float4 f1 = fl4[3 * j4 + 1];
        float4 f2 = fl4[3 * j4 + 2];
        float4 w4 = ((const float4*)W)[j4];

        float l[4][3] = {{f0.x, f0.y, f0.z},
                         {f0.w, f1.x, f1.y},
                         {f1.z, f1.w, f2.x},
                         {f2.y, f2.z, f2.w}};
        float wv[4] = {w4.x, w4.y, w4.z, w4.w};
        const float C[NK] = {TC0, TC1, TC2, TC3, TC4};

        float we[4], tt[4];
#pragma unroll
        for (int e = 0; e < 4; ++e) {
            float e0 = fast_exp2(l[e][0] * LOG2E);
            float e1 = fast_exp2(l[e][1] * LOG2E);
            float e2 = fast_exp2(l[e][2] * LOG2E);
            float inv = fast_rcp(e0 + e1 + e2);
            float w = wv[e];
            float t = w * w;
            float th = w * (1.0f + t * (-0.3333333333f + t * (0.1333333333f + t * (-0.05396825397f))));
            float sn = w * (1.0f + t * (-0.1666666667f + t * (0.008333333333f + t * (-1.984126984e-4f))));
            we[e] = (e0 * w + e1 * th + e2 * sn) * inv;
            tt[e] = we[e] * we[e];
        }
#pragma unroll
        for (int s = 0; s < NK; ++s) {
            ushort4 u = make_ushort4(f2bf(C[s] * we[0]), f2bf(C[s] * we[1]),
                                     f2bf(C[s] * we[2]), f2bf(C[s] * we[3]));
            *(ushort4*)(Bf + (size_t)o * KFEAT + s * IN_DIM + i) = u;
#pragma unroll
            for (int e = 0; e < 4; ++e) we[e] *= tt[e];
        }
    } else {
        const int j4 = (blockIdx.x - 1024) * 256 + threadIdx.x;  // 65536 chunks
        const int b  = j4 >> 8;
        const int i  = (j4 & 255) * 4;
        float4 hv = ((const float4*)h)[j4];
        float x[4] = {hv.x, hv.y, hv.z, hv.w};
        float p[4], t[4];
#pragma unroll
        for (int e = 0; e < 4; ++e) { p[e] = x[e]; t[e] = x[e] * x[e]; }
#pragma unroll
        for (int s = 0; s < NK; ++s) {
            ushort4 u = make_ushort4(f2bf(p[0]), f2bf(p[1]), f2bf(p[2]), f2bf(p[3]));
            *(ushort4*)(Af + (size_t)b * KFEAT + s * IN_DIM + i) = u;
#pragma unroll
            for (int e = 0; e < 4; ++e) p[e] *= t[e];
        }
    }
}

// ---------------------------------------------------------------------------
// Split-K GEMM, no atomics: part[sg] = Af(256x5120).Bf(1024x5120)^T restricted
// to K-segment sg. 512 blocks = 8(global K-seg) x 4(M-tiles) x 16(N-tiles),
// 64x64 tiles -> 2 blocks/CU (lb(256,2), 64KB LDS) = 2 waves/SIMD.
// 4 waves split the block's 640-K segment (160 each = 5 K-steps, fully
// unrolled so all 40 fragment loads are hoistable); LDS tree-reduce then
// ONE plain fp32 store per output into the per-segment partial slab.
// mfma_f32_16x16x32_bf16: A/B frag elem [m|n=lane&15][k=(lane>>4)*8+j];
// C/D: row=(lane>>4)*4+reg, col=lane&15 (verified prev session R4-R6).
// ---------------------------------------------------------------------------
__global__ __launch_bounds__(256, 2) void gemm_feat_kernel(
    const unsigned short* __restrict__ Af,   // (256, 5120)
    const unsigned short* __restrict__ Bf,   // (1024, 5120)
    float* __restrict__ part)                // (8, 256, 1024) fp32 partials
{
    __shared__ float red[4][64 * 64];        // 64 KB -> 2 blocks/CU

    const int bx = blockIdx.x;               // 0..511
    const int sg = bx & 7;                   // global K-segment
    const int tm = (bx >> 3) & 3;            // M-tile (64 rows)
    const int tn = bx >> 5;                  // N-tile (64 cols)
    const int w    = threadIdx.x >> 6;       // local K-split
    const int lane = threadIdx.x & 63;
    const int q    = lane >> 4;
    const int ln   = lane & 15;

    const int kstart = sg * SEGK + w * WSEGK + q * 8;   // in shorts

    const short8* Ar[4];
    const short8* Br[4];
#pragma unroll
    for (int g = 0; g < 4; ++g)
        Ar[g] = (const short8*)(Af + (size_t)(tm * 64 + g * 16 + ln) * KFEAT + kstart);
#pragma unroll
    for (int c = 0; c < 4; ++c)
        Br[c] = (const short8*)(Bf + (size_t)(tn * 64 + c * 16 + ln) * KFEAT + kstart);

    floatx4 acc[4][4];
#pragma unroll
    for (int g = 0; g < 4; ++g)
#pragma unroll
        for (int c = 0; c < 4; ++c) acc[g][c] = (floatx4)(0.0f);

#pragma unroll
    for (int kk = 0; kk < WSEGK; kk += 32) {             // 5 steps, full unroll
        short8 a[4], b[4];
#pragma unroll
        for (int g = 0; g < 4; ++g) a[g] = Ar[g][kk >> 3];
#pragma unroll
        for (int c = 0; c < 4; ++c) b[c] = Br[c][kk >> 3];
#pragma unroll
        for (int g = 0; g < 4; ++g)
#pragma unroll
            for (int c = 0; c < 4; ++c)
                acc[g][c] = __builtin_amdgcn_mfma_f32_16x16x32_bf16(a[g], b[c], acc[g][c], 0, 0, 0);
    }

    // stash this wave's 64x64 fp32 tile in its LDS quadrant
    float* my = &red[w][0];
#pragma unroll
    for (int g = 0; g < 4; ++g)
#pragma unroll
        for (int c = 0; c < 4; ++c)
#pragma unroll
            for (int r = 0; r < 4; ++r)
                my[(g * 16 + q * 4 + r) * 64 + (c * 16 + ln)] = acc[g][c][r];
    __syncthreads();

    // cross-wave reduce + ONE plain store per output; j-major => coalesced
    float* pseg = part + (size_t)sg * (B_DIM * OUT_DIM);
    const int t = threadIdx.x;
#pragma unroll
    for (int j = 0; j < 16; ++j) {
        const int idx = j * 256 + t;                 // 0..4095
        const float v = red[0][idx] + red[1][idx] + red[2][idx] + red[3][idx];
        const int lr = idx >> 6, lc = idx & 63;
        pseg[(size_t)(tm * 64 + lr) * OUT_DIM + tn * 64 + lc] = v;
    }
}

// ---------------------------------------------------------------------------
// out = bias + sum over 8 partial slabs. 9 MB read / 1 MB write ≈ 1.5 µs.
// ---------------------------------------------------------------------------
__global__ __launch_bounds__(256) void reduce_bias_kernel(
    const float* __restrict__ part,          // (8, 256, 1024)
    const float* __restrict__ bias,          // (1024)
    float* __restrict__ out)                 // (256, 1024)
{
    const int j4 = blockIdx.x * 256 + threadIdx.x;       // 65536 float4s
    float4 a = ((const float4*)bias)[j4 & 255];
#pragma unroll
    for (int s = 0; s < NSEG; ++s) {
        float4 p = ((const float4*)part)[s * 65536 + j4];
        a.x += p.x; a.y += p.y; a.z += p.z; a.w += p.w;
    }
    ((float4*)out)[j4] = a;
}

extern "C" void kernel_launch(void* const* d_in, const int* in_sizes, int n_in,
                              void* d_out, int out_size, void* d_ws, size_t ws_size,
                              hipStream_t stream) {
    const float* h  = (const float*)d_in[0];   // (256, 1024)
    const float* W  = (const float*)d_in[1];   // (1024, 1024)
    const float* b  = (const float*)d_in[2];   // (1024,)
    const float* fl = (const float*)d_in[3];   // (1024, 1024, 3)
    float* out = (float*)d_out;                // (256, 1024)

    unsigned short* Af = (unsigned short*)d_ws;           // 2.5 MB
    unsigned short* Bf = Af + (size_t)B_DIM * KFEAT;      // 10 MB
    float* part = (float*)(Bf + (size_t)OUT_DIM * KFEAT); // 8 MB fp32 partials

    feat_fused_kernel<<<1280, 256, 0, stream>>>(h, W, fl, Af, Bf);
    gemm_feat_kernel<<<512, 256, 0, stream>>>(Af, Bf, part);
    reduce_bias_kernel<<<256, 256, 0, stream>>>(part, b, out);
}